// Round 4
// baseline (3085.152 us; speedup 1.0000x reference)
//
#include <hip/hip_runtime.h>
#include <hip/hip_bf16.h>

#define N_NODES 500000
#define NNZ     2000000
#define N_HE    100000
#define N_G     512
#define CH      64

#define SCAN_BLOCK 256
#define SCAN_CHUNK 1024   // 4 items/thread

// ---------------- degree counting ----------------
__global__ void k_count(const int* __restrict__ row, const int* __restrict__ col,
                        int* __restrict__ Dcnt, int* __restrict__ Bcnt) {
    int i = blockIdx.x * blockDim.x + threadIdx.x;
    int stride = gridDim.x * blockDim.x;
    for (; i < NNZ; i += stride) {
        atomicAdd(&Dcnt[row[i]], 1);
        atomicAdd(&Bcnt[col[i]], 1);
    }
}

// ---------------- hierarchical exclusive scan ----------------
__global__ void k_scan1(const int* __restrict__ in, int n, int* __restrict__ bsums) {
    __shared__ int lds[SCAN_BLOCK];
    int base = blockIdx.x * SCAN_CHUNK;
    int t = threadIdx.x;
    int s = 0;
#pragma unroll
    for (int j = 0; j < 4; ++j) { int idx = base + t * 4 + j; if (idx < n) s += in[idx]; }
    lds[t] = s; __syncthreads();
    for (int off = SCAN_BLOCK / 2; off; off >>= 1) {
        if (t < off) lds[t] += lds[t + off];
        __syncthreads();
    }
    if (t == 0) bsums[blockIdx.x] = lds[0];
}

__global__ void k_scan2(int* __restrict__ bsums, int nb) {
    __shared__ int lds[512];
    int t = threadIdx.x;
    int v = (t < nb) ? bsums[t] : 0;
    lds[t] = v; __syncthreads();
    for (int off = 1; off < 512; off <<= 1) {
        int add = (t >= off) ? lds[t - off] : 0;
        __syncthreads();
        lds[t] += add;
        __syncthreads();
    }
    if (t < nb) bsums[t] = lds[t] - v;   // exclusive
}

__global__ void k_scan3(const int* __restrict__ in, int n, const int* __restrict__ bsums,
                        int* __restrict__ outp, int* __restrict__ cursor) {
    __shared__ int lds[SCAN_BLOCK];
    int base = blockIdx.x * SCAN_CHUNK;
    int t = threadIdx.x;
    int v[4]; int s = 0;
#pragma unroll
    for (int j = 0; j < 4; ++j) { int idx = base + t * 4 + j; v[j] = (idx < n) ? in[idx] : 0; s += v[j]; }
    lds[t] = s; __syncthreads();
    for (int off = 1; off < SCAN_BLOCK; off <<= 1) {
        int add = (t >= off) ? lds[t - off] : 0;
        __syncthreads();
        lds[t] += add;
        __syncthreads();
    }
    int pref = bsums[blockIdx.x] + lds[t] - s;
#pragma unroll
    for (int j = 0; j < 4; ++j) {
        int idx = base + t * 4 + j;
        if (idx < n) {
            outp[idx] = pref;
            cursor[idx] = pref;
            pref += v[j];
            if (idx == n - 1) outp[n] = pref;
        }
    }
}

// ---------------- CSR placement (both directions) ----------------
__global__ void k_place(const int* __restrict__ row, const int* __restrict__ col,
                        int* __restrict__ curR, int* __restrict__ curC,
                        int* __restrict__ adjR, int* __restrict__ adjC) {
    int i = blockIdx.x * blockDim.x + threadIdx.x;
    int stride = gridDim.x * blockDim.x;
    for (; i < NNZ; i += stride) {
        int r = row[i], c = col[i];
        int pR = atomicAdd(&curR[r], 1); adjR[pR] = c;   // node -> its hyperedges
        int pC = atomicAdd(&curC[c], 1); adjC[pC] = r;   // hyperedge -> its nodes
    }
}

// ---------------- graph segment bounds (batch is sorted) ----------------
__global__ void k_bounds(const int* __restrict__ batch, int* __restrict__ gstart) {
    int g = blockIdx.x * blockDim.x + threadIdx.x;
    if (g > N_G) return;
    if (g == N_G) { gstart[g] = N_NODES; return; }
    int lo = 0, hi = N_NODES;
    while (lo < hi) {
        int mid = (lo + hi) >> 1;
        if (batch[mid] < g) lo = mid + 1; else hi = mid;
    }
    gstart[g] = lo;
}

// ======== all heavy kernels: 16 lanes (float4) per row, 4 rows per wave ========

// ---------------- dense 64x64 transform: out = in @ W + b ----------------
__global__ void k_transform(const float* __restrict__ in, const float* __restrict__ W,
                            const float* __restrict__ bias, float* __restrict__ out) {
    __shared__ float Wl[CH * CH];
    for (int t = threadIdx.x; t < CH * CH; t += blockDim.x) Wl[t] = W[t];
    __syncthreads();
    const float4* Wl4 = (const float4*)Wl;
    const float4* in4 = (const float4*)in;
    float4* out4 = (float4*)out;
    int li  = threadIdx.x & 15;
    int gid = blockIdx.x * (blockDim.x >> 4) + (threadIdx.x >> 4);
    int ng  = gridDim.x * (blockDim.x >> 4);
    float4 bc = ((const float4*)bias)[li];
    for (int r = gid; r < N_NODES; r += ng) {
        float4 xv = in4[(size_t)r * 16 + li];
        float4 acc = bc;
#pragma unroll
        for (int k0 = 0; k0 < 16; ++k0) {
            float a0 = __shfl(xv.x, k0, 16);
            float a1 = __shfl(xv.y, k0, 16);
            float a2 = __shfl(xv.z, k0, 16);
            float a3 = __shfl(xv.w, k0, 16);
            float4 w0 = Wl4[(k0 * 4 + 0) * 16 + li];
            float4 w1 = Wl4[(k0 * 4 + 1) * 16 + li];
            float4 w2 = Wl4[(k0 * 4 + 2) * 16 + li];
            float4 w3 = Wl4[(k0 * 4 + 3) * 16 + li];
            acc.x = fmaf(a0, w0.x, acc.x); acc.y = fmaf(a0, w0.y, acc.y);
            acc.z = fmaf(a0, w0.z, acc.z); acc.w = fmaf(a0, w0.w, acc.w);
            acc.x = fmaf(a1, w1.x, acc.x); acc.y = fmaf(a1, w1.y, acc.y);
            acc.z = fmaf(a1, w1.z, acc.z); acc.w = fmaf(a1, w1.w, acc.w);
            acc.x = fmaf(a2, w2.x, acc.x); acc.y = fmaf(a2, w2.y, acc.y);
            acc.z = fmaf(a2, w2.z, acc.z); acc.w = fmaf(a2, w2.w, acc.w);
            acc.x = fmaf(a3, w3.x, acc.x); acc.y = fmaf(a3, w3.y, acc.y);
            acc.z = fmaf(a3, w3.z, acc.z); acc.w = fmaf(a3, w3.w, acc.w);
        }
        out4[(size_t)r * 16 + li] = acc;
    }
}

// ---------------- hyperedge pull: m[e] = (sum_{v in e} xt[v]) * Binv[e] ----------------
__global__ void k_he_pull(const float* __restrict__ xt, const int* __restrict__ colptr,
                          const int* __restrict__ adjC, float* __restrict__ m) {
    const float4* xt4 = (const float4*)xt;
    float4* m4 = (float4*)m;
    int li  = threadIdx.x & 15;
    int gid = blockIdx.x * (blockDim.x >> 4) + (threadIdx.x >> 4);
    int ng  = gridDim.x * (blockDim.x >> 4);
    for (int e = gid; e < N_HE; e += ng) {
        int s = colptr[e], en = colptr[e + 1];
        float4 acc = {0.f, 0.f, 0.f, 0.f};
        int p = s;
        for (; p + 8 <= en; p += 8) {
            int c0 = adjC[p], c1 = adjC[p+1], c2 = adjC[p+2], c3 = adjC[p+3];
            int c4 = adjC[p+4], c5 = adjC[p+5], c6 = adjC[p+6], c7 = adjC[p+7];
            float4 v0 = xt4[(size_t)c0 * 16 + li];
            float4 v1 = xt4[(size_t)c1 * 16 + li];
            float4 v2 = xt4[(size_t)c2 * 16 + li];
            float4 v3 = xt4[(size_t)c3 * 16 + li];
            float4 v4 = xt4[(size_t)c4 * 16 + li];
            float4 v5 = xt4[(size_t)c5 * 16 + li];
            float4 v6 = xt4[(size_t)c6 * 16 + li];
            float4 v7 = xt4[(size_t)c7 * 16 + li];
            acc.x += (v0.x + v1.x) + (v2.x + v3.x) + ((v4.x + v5.x) + (v6.x + v7.x));
            acc.y += (v0.y + v1.y) + (v2.y + v3.y) + ((v4.y + v5.y) + (v6.y + v7.y));
            acc.z += (v0.z + v1.z) + (v2.z + v3.z) + ((v4.z + v5.z) + (v6.z + v7.z));
            acc.w += (v0.w + v1.w) + (v2.w + v3.w) + ((v4.w + v5.w) + (v6.w + v7.w));
        }
        for (; p < en; ++p) {
            float4 v = xt4[(size_t)adjC[p] * 16 + li];
            acc.x += v.x; acc.y += v.y; acc.z += v.z; acc.w += v.w;
        }
        float binv = (en > s) ? 1.0f / (float)(en - s) : 0.0f;
        acc.x *= binv; acc.y *= binv; acc.z *= binv; acc.w *= binv;
        m4[(size_t)e * 16 + li] = acc;
    }
}

// helper: pull sum of m rows for node v (unroll 4)
__device__ __forceinline__ float4 pull4(const float4* __restrict__ m4, const int* __restrict__ adj,
                                        int s, int en, int li) {
    float4 acc = {0.f, 0.f, 0.f, 0.f};
    int p = s;
    for (; p + 4 <= en; p += 4) {
        int c0 = adj[p], c1 = adj[p+1], c2 = adj[p+2], c3 = adj[p+3];
        float4 v0 = m4[(size_t)c0 * 16 + li];
        float4 v1 = m4[(size_t)c1 * 16 + li];
        float4 v2 = m4[(size_t)c2 * 16 + li];
        float4 v3 = m4[(size_t)c3 * 16 + li];
        acc.x += (v0.x + v1.x) + (v2.x + v3.x);
        acc.y += (v0.y + v1.y) + (v2.y + v3.y);
        acc.z += (v0.z + v1.z) + (v2.z + v3.z);
        acc.w += (v0.w + v1.w) + (v2.w + v3.w);
    }
    for (; p < en; ++p) {
        float4 v = m4[(size_t)adj[p] * 16 + li];
        acc.x += v.x; acc.y += v.y; acc.z += v.z; acc.w += v.w;
    }
    return acc;
}

// ---------------- node pull + relu(.*Dinv) + transform ----------------
__global__ void k_node_pull_xform(const float* __restrict__ m, const int* __restrict__ rowptr,
                                  const int* __restrict__ adjR, const float* __restrict__ W,
                                  const float* __restrict__ bias, float* __restrict__ out) {
    __shared__ float Wl[CH * CH];
    for (int t = threadIdx.x; t < CH * CH; t += blockDim.x) Wl[t] = W[t];
    __syncthreads();
    const float4* Wl4 = (const float4*)Wl;
    const float4* m4 = (const float4*)m;
    float4* out4 = (float4*)out;
    int li  = threadIdx.x & 15;
    int gid = blockIdx.x * (blockDim.x >> 4) + (threadIdx.x >> 4);
    int ng  = gridDim.x * (blockDim.x >> 4);
    float4 bc = ((const float4*)bias)[li];
    for (int v = gid; v < N_NODES; v += ng) {
        int s = rowptr[v], en = rowptr[v + 1];
        float4 h = pull4(m4, adjR, s, en, li);
        float dinv = (en > s) ? 1.0f / (float)(en - s) : 0.0f;
        h.x = fmaxf(h.x * dinv, 0.0f); h.y = fmaxf(h.y * dinv, 0.0f);
        h.z = fmaxf(h.z * dinv, 0.0f); h.w = fmaxf(h.w * dinv, 0.0f);
        float4 acc = bc;
#pragma unroll
        for (int k0 = 0; k0 < 16; ++k0) {
            float a0 = __shfl(h.x, k0, 16);
            float a1 = __shfl(h.y, k0, 16);
            float a2 = __shfl(h.z, k0, 16);
            float a3 = __shfl(h.w, k0, 16);
            float4 w0 = Wl4[(k0 * 4 + 0) * 16 + li];
            float4 w1 = Wl4[(k0 * 4 + 1) * 16 + li];
            float4 w2 = Wl4[(k0 * 4 + 2) * 16 + li];
            float4 w3 = Wl4[(k0 * 4 + 3) * 16 + li];
            acc.x = fmaf(a0, w0.x, acc.x); acc.y = fmaf(a0, w0.y, acc.y);
            acc.z = fmaf(a0, w0.z, acc.z); acc.w = fmaf(a0, w0.w, acc.w);
            acc.x = fmaf(a1, w1.x, acc.x); acc.y = fmaf(a1, w1.y, acc.y);
            acc.z = fmaf(a1, w1.z, acc.z); acc.w = fmaf(a1, w1.w, acc.w);
            acc.x = fmaf(a2, w2.x, acc.x); acc.y = fmaf(a2, w2.y, acc.y);
            acc.z = fmaf(a2, w2.z, acc.z); acc.w = fmaf(a2, w2.w, acc.w);
            acc.x = fmaf(a3, w3.x, acc.x); acc.y = fmaf(a3, w3.y, acc.y);
            acc.z = fmaf(a3, w3.z, acc.z); acc.w = fmaf(a3, w3.w, acc.w);
        }
        out4[(size_t)v * 16 + li] = acc;
    }
}

// ---------------- node pull + relu(.*Dinv) + mean-pool accumulate ----------------
// contiguous node range per 16-lane group preserves sorted-batch run-length logic
__global__ void k_node_pull_pool(const float* __restrict__ m, const int* __restrict__ rowptr,
                                 const int* __restrict__ adjR, const int* __restrict__ batch,
                                 float* __restrict__ pooled) {
    const float4* m4 = (const float4*)m;
    int li  = threadIdx.x & 15;
    int gid = blockIdx.x * (blockDim.x >> 4) + (threadIdx.x >> 4);
    int ng  = gridDim.x * (blockDim.x >> 4);
    int per = (N_NODES + ng - 1) / ng;
    int start = gid * per;
    int end = start + per; if (end > N_NODES) end = N_NODES;
    if (start >= end) return;
    float4 acc = {0.f, 0.f, 0.f, 0.f};
    int cur = batch[start];
    for (int v = start; v < end; ++v) {
        int s = rowptr[v], en = rowptr[v + 1];
        float4 h = pull4(m4, adjR, s, en, li);
        float dinv = (en > s) ? 1.0f / (float)(en - s) : 0.0f;
        int b = batch[v];
        if (b != cur) {
            float* dst = &pooled[(size_t)cur * CH + li * 4];
            atomicAdd(dst + 0, acc.x); atomicAdd(dst + 1, acc.y);
            atomicAdd(dst + 2, acc.z); atomicAdd(dst + 3, acc.w);
            acc.x = acc.y = acc.z = acc.w = 0.f;
            cur = b;
        }
        acc.x += fmaxf(h.x * dinv, 0.0f); acc.y += fmaxf(h.y * dinv, 0.0f);
        acc.z += fmaxf(h.z * dinv, 0.0f); acc.w += fmaxf(h.w * dinv, 0.0f);
    }
    float* dst = &pooled[(size_t)cur * CH + li * 4];
    atomicAdd(dst + 0, acc.x); atomicAdd(dst + 1, acc.y);
    atomicAdd(dst + 2, acc.z); atomicAdd(dst + 3, acc.w);
}

// ---------------- final: out[g] = (pooled[g]/max(cnt,1)) . Wfc + bfc ----------------
__global__ void k_final(const float* __restrict__ pooled, const int* __restrict__ gstart,
                        const float* __restrict__ Wfc, const float* __restrict__ bfc,
                        float* __restrict__ out) {
    int g = blockIdx.x;
    int lane = threadIdx.x;  // 64 threads
    float cnt = (float)(gstart[g + 1] - gstart[g]);
    cnt = fmaxf(cnt, 1.0f);
    float s = pooled[(size_t)g * CH + lane] / cnt;
    float p = s * Wfc[lane];
#pragma unroll
    for (int off = 32; off; off >>= 1) p += __shfl_down(p, off);
    if (lane == 0) out[g] = p + bfc[0];
}

extern "C" void kernel_launch(void* const* d_in, const int* in_sizes, int n_in,
                              void* d_out, int out_size, void* d_ws, size_t ws_size,
                              hipStream_t stream) {
    const float* x     = (const float*)d_in[0];
    const int*   ei    = (const int*)d_in[1];
    const int*   batch = (const int*)d_in[2];
    const float* W1    = (const float*)d_in[3];
    const float* b1    = (const float*)d_in[4];
    const float* W2    = (const float*)d_in[5];
    const float* b2    = (const float*)d_in[6];
    const float* Wfc   = (const float*)d_in[7];
    const float* bfc   = (const float*)d_in[8];
    float* out = (float*)d_out;

    const int* row = ei;
    const int* col = ei + NNZ;

    // ---- workspace carve-up (all offsets 256B-aligned) ----
    char* ws = (char*)d_ws;
    size_t off = 0;
    auto carve = [&](size_t bytes) {
        void* p = ws + off;
        off += (bytes + 255) & ~(size_t)255;
        return p;
    };
    float* bufA   = (float*)carve((size_t)N_NODES * CH * sizeof(float));  // 128 MB
    float* bufM   = (float*)carve((size_t)N_HE * CH * sizeof(float));     // 25.6 MB
    int*   adjR   = (int*)carve((size_t)NNZ * sizeof(int));               // 8 MB
    int*   adjC   = (int*)carve((size_t)NNZ * sizeof(int));               // 8 MB
    int*   Dcnt   = (int*)carve((size_t)N_NODES * sizeof(int));
    int*   Bcnt   = (int*)carve((size_t)N_HE * sizeof(int));
    int*   rowptr = (int*)carve((size_t)(N_NODES + 1) * sizeof(int));
    int*   colptr = (int*)carve((size_t)(N_HE + 1) * sizeof(int));
    int*   curR   = (int*)carve((size_t)N_NODES * sizeof(int));
    int*   curC   = (int*)carve((size_t)N_HE * sizeof(int));
    int*   bsR    = (int*)carve(512 * sizeof(int));
    int*   bsC    = (int*)carve(512 * sizeof(int));
    int*   gstart = (int*)carve((size_t)(N_G + 1) * sizeof(int));
    float* pooled = (float*)carve((size_t)N_G * CH * sizeof(float));

    const int nbR = (N_NODES + SCAN_CHUNK - 1) / SCAN_CHUNK;  // 489
    const int nbC = (N_HE + SCAN_CHUNK - 1) / SCAN_CHUNK;     // 98

    hipMemsetAsync(Dcnt, 0, (size_t)N_NODES * sizeof(int), stream);
    hipMemsetAsync(Bcnt, 0, (size_t)N_HE * sizeof(int), stream);
    hipMemsetAsync(pooled, 0, (size_t)N_G * CH * sizeof(float), stream);

    // build CSR both directions
    k_count<<<2048, 256, 0, stream>>>(row, col, Dcnt, Bcnt);
    k_scan1<<<nbR, SCAN_BLOCK, 0, stream>>>(Dcnt, N_NODES, bsR);
    k_scan2<<<1, 512, 0, stream>>>(bsR, nbR);
    k_scan3<<<nbR, SCAN_BLOCK, 0, stream>>>(Dcnt, N_NODES, bsR, rowptr, curR);
    k_scan1<<<nbC, SCAN_BLOCK, 0, stream>>>(Bcnt, N_HE, bsC);
    k_scan2<<<1, 512, 0, stream>>>(bsC, nbC);
    k_scan3<<<nbC, SCAN_BLOCK, 0, stream>>>(Bcnt, N_HE, bsC, colptr, curC);
    k_place<<<2048, 256, 0, stream>>>(row, col, curR, curC, adjR, adjC);
    k_bounds<<<3, 256, 0, stream>>>(batch, gstart);

    // conv1: xt = x@W1+b1; m = pull(xt)*Binv
    k_transform<<<2048, 256, 0, stream>>>(x, W1, b1, bufA);
    k_he_pull<<<2048, 256, 0, stream>>>(bufA, colptr, adjC, bufM);
    // conv2 input transform fused with conv1's node-pull
    k_node_pull_xform<<<2048, 256, 0, stream>>>(bufM, rowptr, adjR, W2, b2, bufA);
    // conv2: m2 = pull(bufA)*Binv
    k_he_pull<<<2048, 256, 0, stream>>>(bufA, colptr, adjC, bufM);
    // conv2 node-pull fused with mean-pool accumulation
    k_node_pull_pool<<<2048, 256, 0, stream>>>(bufM, rowptr, adjR, batch, pooled);
    k_final<<<N_G, 64, 0, stream>>>(pooled, gstart, Wfc, bfc, out);
}

// Round 6
// 1311.391 us; speedup vs baseline: 2.3526x; 2.3526x over previous
//
#include <hip/hip_runtime.h>
#include <hip/hip_bf16.h>

#define N_NODES 500000
#define NNZ     2000000
#define N_HE    100000
#define N_G     512
#define CH      64

#define SCAN_BLOCK 256
#define SCAN_CHUNK 1024   // 4 items/thread

// ---------------- degree counting ----------------
__global__ void k_count(const int* __restrict__ row, const int* __restrict__ col,
                        int* __restrict__ Dcnt, int* __restrict__ Bcnt) {
    int i = blockIdx.x * blockDim.x + threadIdx.x;
    int stride = gridDim.x * blockDim.x;
    for (; i < NNZ; i += stride) {
        atomicAdd(&Dcnt[row[i]], 1);
        atomicAdd(&Bcnt[col[i]], 1);
    }
}

// ---------------- hierarchical exclusive scan ----------------
__global__ void k_scan1(const int* __restrict__ in, int n, int* __restrict__ bsums) {
    __shared__ int lds[SCAN_BLOCK];
    int base = blockIdx.x * SCAN_CHUNK;
    int t = threadIdx.x;
    int s = 0;
#pragma unroll
    for (int j = 0; j < 4; ++j) { int idx = base + t * 4 + j; if (idx < n) s += in[idx]; }
    lds[t] = s; __syncthreads();
    for (int off = SCAN_BLOCK / 2; off; off >>= 1) {
        if (t < off) lds[t] += lds[t + off];
        __syncthreads();
    }
    if (t == 0) bsums[blockIdx.x] = lds[0];
}

__global__ void k_scan2(int* __restrict__ bsums, int nb) {
    __shared__ int lds[512];
    int t = threadIdx.x;
    int v = (t < nb) ? bsums[t] : 0;
    lds[t] = v; __syncthreads();
    for (int off = 1; off < 512; off <<= 1) {
        int add = (t >= off) ? lds[t - off] : 0;
        __syncthreads();
        lds[t] += add;
        __syncthreads();
    }
    if (t < nb) bsums[t] = lds[t] - v;   // exclusive
}

__global__ void k_scan3(const int* __restrict__ in, int n, const int* __restrict__ bsums,
                        int* __restrict__ outp, int* __restrict__ cursor) {
    __shared__ int lds[SCAN_BLOCK];
    int base = blockIdx.x * SCAN_CHUNK;
    int t = threadIdx.x;
    int v[4]; int s = 0;
#pragma unroll
    for (int j = 0; j < 4; ++j) { int idx = base + t * 4 + j; v[j] = (idx < n) ? in[idx] : 0; s += v[j]; }
    lds[t] = s; __syncthreads();
    for (int off = 1; off < SCAN_BLOCK; off <<= 1) {
        int add = (t >= off) ? lds[t - off] : 0;
        __syncthreads();
        lds[t] += add;
        __syncthreads();
    }
    int pref = bsums[blockIdx.x] + lds[t] - s;
#pragma unroll
    for (int j = 0; j < 4; ++j) {
        int idx = base + t * 4 + j;
        if (idx < n) {
            outp[idx] = pref;
            cursor[idx] = pref;
            pref += v[j];
            if (idx == n - 1) outp[n] = pref;
        }
    }
}

// ---------------- CSR placement (both directions) ----------------
__global__ void k_place(const int* __restrict__ row, const int* __restrict__ col,
                        int* __restrict__ curR, int* __restrict__ curC,
                        int* __restrict__ adjR, int* __restrict__ adjC) {
    int i = blockIdx.x * blockDim.x + threadIdx.x;
    int stride = gridDim.x * blockDim.x;
    for (; i < NNZ; i += stride) {
        int r = row[i], c = col[i];
        int pR = atomicAdd(&curR[r], 1); adjR[pR] = c;   // node -> its hyperedges
        int pC = atomicAdd(&curC[c], 1); adjC[pC] = r;   // hyperedge -> its nodes
    }
}

// ---------------- graph segment bounds (batch is sorted) ----------------
__global__ void k_bounds(const int* __restrict__ batch, int* __restrict__ gstart) {
    int g = blockIdx.x * blockDim.x + threadIdx.x;
    if (g > N_G) return;
    if (g == N_G) { gstart[g] = N_NODES; return; }
    int lo = 0, hi = N_NODES;
    while (lo < hi) {
        int mid = (lo + hi) >> 1;
        if (batch[mid] < g) lo = mid + 1; else hi = mid;
    }
    gstart[g] = lo;
}

// ======== heavy kernels: 16 lanes (float4) per row, 4 rows per wave ========
// NOTE: the W-transform loops use "#pragma unroll 2" deliberately. Full unroll
// exposes all 64 loop-invariant W float4 LDS reads; LICM hoists them past the
// VGPR budget and spills to scratch -> 3.5 GB of HBM scratch traffic (round 4).

// ---------------- dense 64x64 transform: out = in @ W + b ----------------
__global__ void k_transform(const float* __restrict__ in, const float* __restrict__ W,
                            const float* __restrict__ bias, float* __restrict__ out) {
    __shared__ float Wl[CH * CH];
    for (int t = threadIdx.x; t < CH * CH; t += blockDim.x) Wl[t] = W[t];
    __syncthreads();
    const float4* Wl4 = (const float4*)Wl;
    const float4* in4 = (const float4*)in;
    float4* out4 = (float4*)out;
    int li  = threadIdx.x & 15;
    int gid = blockIdx.x * (blockDim.x >> 4) + (threadIdx.x >> 4);
    int ng  = gridDim.x * (blockDim.x >> 4);
    float4 bc = ((const float4*)bias)[li];
    for (int r = gid; r < N_NODES; r += ng) {
        float4 xv = in4[(size_t)r * 16 + li];
        float4 acc = bc;
#pragma unroll 2
        for (int k0 = 0; k0 < 16; ++k0) {
            float a0 = __shfl(xv.x, k0, 16);
            float a1 = __shfl(xv.y, k0, 16);
            float a2 = __shfl(xv.z, k0, 16);
            float a3 = __shfl(xv.w, k0, 16);
            float4 w0 = Wl4[(k0 * 4 + 0) * 16 + li];
            float4 w1 = Wl4[(k0 * 4 + 1) * 16 + li];
            float4 w2 = Wl4[(k0 * 4 + 2) * 16 + li];
            float4 w3 = Wl4[(k0 * 4 + 3) * 16 + li];
            acc.x = fmaf(a0, w0.x, acc.x); acc.y = fmaf(a0, w0.y, acc.y);
            acc.z = fmaf(a0, w0.z, acc.z); acc.w = fmaf(a0, w0.w, acc.w);
            acc.x = fmaf(a1, w1.x, acc.x); acc.y = fmaf(a1, w1.y, acc.y);
            acc.z = fmaf(a1, w1.z, acc.z); acc.w = fmaf(a1, w1.w, acc.w);
            acc.x = fmaf(a2, w2.x, acc.x); acc.y = fmaf(a2, w2.y, acc.y);
            acc.z = fmaf(a2, w2.z, acc.z); acc.w = fmaf(a2, w2.w, acc.w);
            acc.x = fmaf(a3, w3.x, acc.x); acc.y = fmaf(a3, w3.y, acc.y);
            acc.z = fmaf(a3, w3.z, acc.z); acc.w = fmaf(a3, w3.w, acc.w);
        }
        out4[(size_t)r * 16 + li] = acc;
    }
}

// ---------------- hyperedge pull: m[e] = (sum_{v in e} xt[v]) * Binv[e] ----------------
__global__ void k_he_pull(const float* __restrict__ xt, const int* __restrict__ colptr,
                          const int* __restrict__ adjC, float* __restrict__ m) {
    const float4* xt4 = (const float4*)xt;
    float4* m4 = (float4*)m;
    int li  = threadIdx.x & 15;
    int gid = blockIdx.x * (blockDim.x >> 4) + (threadIdx.x >> 4);
    int ng  = gridDim.x * (blockDim.x >> 4);
    for (int e = gid; e < N_HE; e += ng) {
        int s = colptr[e], en = colptr[e + 1];
        float4 acc = {0.f, 0.f, 0.f, 0.f};
        int p = s;
        for (; p + 8 <= en; p += 8) {
            int c0 = adjC[p], c1 = adjC[p+1], c2 = adjC[p+2], c3 = adjC[p+3];
            int c4 = adjC[p+4], c5 = adjC[p+5], c6 = adjC[p+6], c7 = adjC[p+7];
            float4 v0 = xt4[(size_t)c0 * 16 + li];
            float4 v1 = xt4[(size_t)c1 * 16 + li];
            float4 v2 = xt4[(size_t)c2 * 16 + li];
            float4 v3 = xt4[(size_t)c3 * 16 + li];
            float4 v4 = xt4[(size_t)c4 * 16 + li];
            float4 v5 = xt4[(size_t)c5 * 16 + li];
            float4 v6 = xt4[(size_t)c6 * 16 + li];
            float4 v7 = xt4[(size_t)c7 * 16 + li];
            acc.x += (v0.x + v1.x) + (v2.x + v3.x) + ((v4.x + v5.x) + (v6.x + v7.x));
            acc.y += (v0.y + v1.y) + (v2.y + v3.y) + ((v4.y + v5.y) + (v6.y + v7.y));
            acc.z += (v0.z + v1.z) + (v2.z + v3.z) + ((v4.z + v5.z) + (v6.z + v7.z));
            acc.w += (v0.w + v1.w) + (v2.w + v3.w) + ((v4.w + v5.w) + (v6.w + v7.w));
        }
        for (; p < en; ++p) {
            float4 v = xt4[(size_t)adjC[p] * 16 + li];
            acc.x += v.x; acc.y += v.y; acc.z += v.z; acc.w += v.w;
        }
        float binv = (en > s) ? 1.0f / (float)(en - s) : 0.0f;
        acc.x *= binv; acc.y *= binv; acc.z *= binv; acc.w *= binv;
        m4[(size_t)e * 16 + li] = acc;
    }
}

// helper: pull sum of m rows for node v (unroll 4)
__device__ __forceinline__ float4 pull4(const float4* __restrict__ m4, const int* __restrict__ adj,
                                        int s, int en, int li) {
    float4 acc = {0.f, 0.f, 0.f, 0.f};
    int p = s;
    for (; p + 4 <= en; p += 4) {
        int c0 = adj[p], c1 = adj[p+1], c2 = adj[p+2], c3 = adj[p+3];
        float4 v0 = m4[(size_t)c0 * 16 + li];
        float4 v1 = m4[(size_t)c1 * 16 + li];
        float4 v2 = m4[(size_t)c2 * 16 + li];
        float4 v3 = m4[(size_t)c3 * 16 + li];
        acc.x += (v0.x + v1.x) + (v2.x + v3.x);
        acc.y += (v0.y + v1.y) + (v2.y + v3.y);
        acc.z += (v0.z + v1.z) + (v2.z + v3.z);
        acc.w += (v0.w + v1.w) + (v2.w + v3.w);
    }
    for (; p < en; ++p) {
        float4 v = m4[(size_t)adj[p] * 16 + li];
        acc.x += v.x; acc.y += v.y; acc.z += v.z; acc.w += v.w;
    }
    return acc;
}

// ---------------- node pull + relu(.*Dinv) + transform ----------------
__global__ void k_node_pull_xform(const float* __restrict__ m, const int* __restrict__ rowptr,
                                  const int* __restrict__ adjR, const float* __restrict__ W,
                                  const float* __restrict__ bias, float* __restrict__ out) {
    __shared__ float Wl[CH * CH];
    for (int t = threadIdx.x; t < CH * CH; t += blockDim.x) Wl[t] = W[t];
    __syncthreads();
    const float4* Wl4 = (const float4*)Wl;
    const float4* m4 = (const float4*)m;
    float4* out4 = (float4*)out;
    int li  = threadIdx.x & 15;
    int gid = blockIdx.x * (blockDim.x >> 4) + (threadIdx.x >> 4);
    int ng  = gridDim.x * (blockDim.x >> 4);
    float4 bc = ((const float4*)bias)[li];
    for (int v = gid; v < N_NODES; v += ng) {
        int s = rowptr[v], en = rowptr[v + 1];
        float4 h = pull4(m4, adjR, s, en, li);
        float dinv = (en > s) ? 1.0f / (float)(en - s) : 0.0f;
        h.x = fmaxf(h.x * dinv, 0.0f); h.y = fmaxf(h.y * dinv, 0.0f);
        h.z = fmaxf(h.z * dinv, 0.0f); h.w = fmaxf(h.w * dinv, 0.0f);
        float4 acc = bc;
#pragma unroll 2
        for (int k0 = 0; k0 < 16; ++k0) {
            float a0 = __shfl(h.x, k0, 16);
            float a1 = __shfl(h.y, k0, 16);
            float a2 = __shfl(h.z, k0, 16);
            float a3 = __shfl(h.w, k0, 16);
            float4 w0 = Wl4[(k0 * 4 + 0) * 16 + li];
            float4 w1 = Wl4[(k0 * 4 + 1) * 16 + li];
            float4 w2 = Wl4[(k0 * 4 + 2) * 16 + li];
            float4 w3 = Wl4[(k0 * 4 + 3) * 16 + li];
            acc.x = fmaf(a0, w0.x, acc.x); acc.y = fmaf(a0, w0.y, acc.y);
            acc.z = fmaf(a0, w0.z, acc.z); acc.w = fmaf(a0, w0.w, acc.w);
            acc.x = fmaf(a1, w1.x, acc.x); acc.y = fmaf(a1, w1.y, acc.y);
            acc.z = fmaf(a1, w1.z, acc.z); acc.w = fmaf(a1, w1.w, acc.w);
            acc.x = fmaf(a2, w2.x, acc.x); acc.y = fmaf(a2, w2.y, acc.y);
            acc.z = fmaf(a2, w2.z, acc.z); acc.w = fmaf(a2, w2.w, acc.w);
            acc.x = fmaf(a3, w3.x, acc.x); acc.y = fmaf(a3, w3.y, acc.y);
            acc.z = fmaf(a3, w3.z, acc.z); acc.w = fmaf(a3, w3.w, acc.w);
        }
        out4[(size_t)v * 16 + li] = acc;
    }
}

// ---------------- node pull + relu(.*Dinv) + mean-pool accumulate ----------------
__global__ void k_node_pull_pool(const float* __restrict__ m, const int* __restrict__ rowptr,
                                 const int* __restrict__ adjR, const int* __restrict__ batch,
                                 float* __restrict__ pooled) {
    const float4* m4 = (const float4*)m;
    int li  = threadIdx.x & 15;
    int gid = blockIdx.x * (blockDim.x >> 4) + (threadIdx.x >> 4);
    int ng  = gridDim.x * (blockDim.x >> 4);
    int per = (N_NODES + ng - 1) / ng;
    int start = gid * per;
    int end = start + per; if (end > N_NODES) end = N_NODES;
    if (start >= end) return;
    float4 acc = {0.f, 0.f, 0.f, 0.f};
    int cur = batch[start];
    for (int v = start; v < end; ++v) {
        int s = rowptr[v], en = rowptr[v + 1];
        float4 h = pull4(m4, adjR, s, en, li);
        float dinv = (en > s) ? 1.0f / (float)(en - s) : 0.0f;
        int b = batch[v];
        if (b != cur) {
            float* dst = &pooled[(size_t)cur * CH + li * 4];
            atomicAdd(dst + 0, acc.x); atomicAdd(dst + 1, acc.y);
            atomicAdd(dst + 2, acc.z); atomicAdd(dst + 3, acc.w);
            acc.x = acc.y = acc.z = acc.w = 0.f;
            cur = b;
        }
        acc.x += fmaxf(h.x * dinv, 0.0f); acc.y += fmaxf(h.y * dinv, 0.0f);
        acc.z += fmaxf(h.z * dinv, 0.0f); acc.w += fmaxf(h.w * dinv, 0.0f);
    }
    float* dst = &pooled[(size_t)cur * CH + li * 4];
    atomicAdd(dst + 0, acc.x); atomicAdd(dst + 1, acc.y);
    atomicAdd(dst + 2, acc.z); atomicAdd(dst + 3, acc.w);
}

// ---------------- final: out[g] = (pooled[g]/max(cnt,1)) . Wfc + bfc ----------------
__global__ void k_final(const float* __restrict__ pooled, const int* __restrict__ gstart,
                        const float* __restrict__ Wfc, const float* __restrict__ bfc,
                        float* __restrict__ out) {
    int g = blockIdx.x;
    int lane = threadIdx.x;  // 64 threads
    float cnt = (float)(gstart[g + 1] - gstart[g]);
    cnt = fmaxf(cnt, 1.0f);
    float s = pooled[(size_t)g * CH + lane] / cnt;
    float p = s * Wfc[lane];
#pragma unroll
    for (int off = 32; off; off >>= 1) p += __shfl_down(p, off);
    if (lane == 0) out[g] = p + bfc[0];
}

extern "C" void kernel_launch(void* const* d_in, const int* in_sizes, int n_in,
                              void* d_out, int out_size, void* d_ws, size_t ws_size,
                              hipStream_t stream) {
    const float* x     = (const float*)d_in[0];
    const int*   ei    = (const int*)d_in[1];
    const int*   batch = (const int*)d_in[2];
    const float* W1    = (const float*)d_in[3];
    const float* b1    = (const float*)d_in[4];
    const float* W2    = (const float*)d_in[5];
    const float* b2    = (const float*)d_in[6];
    const float* Wfc   = (const float*)d_in[7];
    const float* bfc   = (const float*)d_in[8];
    float* out = (float*)d_out;

    const int* row = ei;
    const int* col = ei + NNZ;

    // ---- workspace carve-up (all offsets 256B-aligned) ----
    char* ws = (char*)d_ws;
    size_t off = 0;
    auto carve = [&](size_t bytes) {
        void* p = ws + off;
        off += (bytes + 255) & ~(size_t)255;
        return p;
    };
    float* bufA   = (float*)carve((size_t)N_NODES * CH * sizeof(float));  // 128 MB
    float* bufM   = (float*)carve((size_t)N_HE * CH * sizeof(float));     // 25.6 MB
    int*   adjR   = (int*)carve((size_t)NNZ * sizeof(int));               // 8 MB
    int*   adjC   = (int*)carve((size_t)NNZ * sizeof(int));               // 8 MB
    int*   Dcnt   = (int*)carve((size_t)N_NODES * sizeof(int));
    int*   Bcnt   = (int*)carve((size_t)N_HE * sizeof(int));
    int*   rowptr = (int*)carve((size_t)(N_NODES + 1) * sizeof(int));
    int*   colptr = (int*)carve((size_t)(N_HE + 1) * sizeof(int));
    int*   curR   = (int*)carve((size_t)N_NODES * sizeof(int));
    int*   curC   = (int*)carve((size_t)N_HE * sizeof(int));
    int*   bsR    = (int*)carve(512 * sizeof(int));
    int*   bsC    = (int*)carve(512 * sizeof(int));
    int*   gstart = (int*)carve((size_t)(N_G + 1) * sizeof(int));
    float* pooled = (float*)carve((size_t)N_G * CH * sizeof(float));

    const int nbR = (N_NODES + SCAN_CHUNK - 1) / SCAN_CHUNK;  // 489
    const int nbC = (N_HE + SCAN_CHUNK - 1) / SCAN_CHUNK;     // 98

    hipMemsetAsync(Dcnt, 0, (size_t)N_NODES * sizeof(int), stream);
    hipMemsetAsync(Bcnt, 0, (size_t)N_HE * sizeof(int), stream);
    hipMemsetAsync(pooled, 0, (size_t)N_G * CH * sizeof(float), stream);

    // build CSR both directions
    k_count<<<2048, 256, 0, stream>>>(row, col, Dcnt, Bcnt);
    k_scan1<<<nbR, SCAN_BLOCK, 0, stream>>>(Dcnt, N_NODES, bsR);
    k_scan2<<<1, 512, 0, stream>>>(bsR, nbR);
    k_scan3<<<nbR, SCAN_BLOCK, 0, stream>>>(Dcnt, N_NODES, bsR, rowptr, curR);
    k_scan1<<<nbC, SCAN_BLOCK, 0, stream>>>(Bcnt, N_HE, bsC);
    k_scan2<<<1, 512, 0, stream>>>(bsC, nbC);
    k_scan3<<<nbC, SCAN_BLOCK, 0, stream>>>(Bcnt, N_HE, bsC, colptr, curC);
    k_place<<<2048, 256, 0, stream>>>(row, col, curR, curC, adjR, adjC);
    k_bounds<<<3, 256, 0, stream>>>(batch, gstart);

    // conv1: xt = x@W1+b1; m = pull(xt)*Binv
    k_transform<<<2048, 256, 0, stream>>>(x, W1, b1, bufA);
    k_he_pull<<<2048, 256, 0, stream>>>(bufA, colptr, adjC, bufM);
    // conv2 input transform fused with conv1's node-pull
    k_node_pull_xform<<<2048, 256, 0, stream>>>(bufM, rowptr, adjR, W2, b2, bufA);
    // conv2: m2 = pull(bufA)*Binv
    k_he_pull<<<2048, 256, 0, stream>>>(bufA, colptr, adjC, bufM);
    // conv2 node-pull fused with mean-pool accumulation
    k_node_pull_pool<<<2048, 256, 0, stream>>>(bufM, rowptr, adjR, batch, pooled);
    k_final<<<N_G, 64, 0, stream>>>(pooled, gstart, Wfc, bfc, out);
}

// Round 7
// 1124.750 us; speedup vs baseline: 2.7430x; 1.1659x over previous
//
#include <hip/hip_runtime.h>
#include <hip/hip_bf16.h>

#define N_NODES 500000
#define NNZ     2000000
#define N_HE    100000
#define N_G     512
#define CH      64

#define SCAN_BLOCK 256
#define SCAN_CHUNK 1024   // 4 items/thread

// ---------------- degree counting ----------------
__global__ void k_count(const int* __restrict__ row, const int* __restrict__ col,
                        int* __restrict__ Dcnt, int* __restrict__ Bcnt) {
    int i = blockIdx.x * blockDim.x + threadIdx.x;
    int stride = gridDim.x * blockDim.x;
    for (; i < NNZ; i += stride) {
        atomicAdd(&Dcnt[row[i]], 1);
        atomicAdd(&Bcnt[col[i]], 1);
    }
}

// ---------------- hierarchical exclusive scan ----------------
__global__ void k_scan1(const int* __restrict__ in, int n, int* __restrict__ bsums) {
    __shared__ int lds[SCAN_BLOCK];
    int base = blockIdx.x * SCAN_CHUNK;
    int t = threadIdx.x;
    int s = 0;
#pragma unroll
    for (int j = 0; j < 4; ++j) { int idx = base + t * 4 + j; if (idx < n) s += in[idx]; }
    lds[t] = s; __syncthreads();
    for (int off = SCAN_BLOCK / 2; off; off >>= 1) {
        if (t < off) lds[t] += lds[t + off];
        __syncthreads();
    }
    if (t == 0) bsums[blockIdx.x] = lds[0];
}

__global__ void k_scan2(int* __restrict__ bsums, int nb) {
    __shared__ int lds[512];
    int t = threadIdx.x;
    int v = (t < nb) ? bsums[t] : 0;
    lds[t] = v; __syncthreads();
    for (int off = 1; off < 512; off <<= 1) {
        int add = (t >= off) ? lds[t - off] : 0;
        __syncthreads();
        lds[t] += add;
        __syncthreads();
    }
    if (t < nb) bsums[t] = lds[t] - v;   // exclusive
}

__global__ void k_scan3(const int* __restrict__ in, int n, const int* __restrict__ bsums,
                        int* __restrict__ outp, int* __restrict__ cursor) {
    __shared__ int lds[SCAN_BLOCK];
    int base = blockIdx.x * SCAN_CHUNK;
    int t = threadIdx.x;
    int v[4]; int s = 0;
#pragma unroll
    for (int j = 0; j < 4; ++j) { int idx = base + t * 4 + j; v[j] = (idx < n) ? in[idx] : 0; s += v[j]; }
    lds[t] = s; __syncthreads();
    for (int off = 1; off < SCAN_BLOCK; off <<= 1) {
        int add = (t >= off) ? lds[t - off] : 0;
        __syncthreads();
        lds[t] += add;
        __syncthreads();
    }
    int pref = bsums[blockIdx.x] + lds[t] - s;
#pragma unroll
    for (int j = 0; j < 4; ++j) {
        int idx = base + t * 4 + j;
        if (idx < n) {
            outp[idx] = pref;
            cursor[idx] = pref;
            pref += v[j];
            if (idx == n - 1) outp[n] = pref;
        }
    }
}

// ---------------- CSR placement (both directions, non-temporal scatter) ----------------
__global__ void k_place(const int* __restrict__ row, const int* __restrict__ col,
                        int* __restrict__ curR, int* __restrict__ curC,
                        int* __restrict__ adjR, int* __restrict__ adjC) {
    int i = blockIdx.x * blockDim.x + threadIdx.x;
    int stride = gridDim.x * blockDim.x;
    for (; i < NNZ; i += stride) {
        int r = row[i], c = col[i];
        int pR = atomicAdd(&curR[r], 1);
        __builtin_nontemporal_store(c, &adjR[pR]);   // node -> its hyperedges
        int pC = atomicAdd(&curC[c], 1);
        __builtin_nontemporal_store(r, &adjC[pC]);   // hyperedge -> its nodes
    }
}

// ---------------- graph segment bounds (batch is sorted) ----------------
__global__ void k_bounds(const int* __restrict__ batch, int* __restrict__ gstart) {
    int g = blockIdx.x * blockDim.x + threadIdx.x;
    if (g > N_G) return;
    if (g == N_G) { gstart[g] = N_NODES; return; }
    int lo = 0, hi = N_NODES;
    while (lo < hi) {
        int mid = (lo + hi) >> 1;
        if (batch[mid] < g) lo = mid + 1; else hi = mid;
    }
    gstart[g] = lo;
}

// ======== heavy kernels: 16 lanes (float4) per row, 4 rows per wave ========
// NOTE: W-matmul loops use "#pragma unroll 2" deliberately. Full unroll exposes
// all 64 loop-invariant W float4 LDS reads; LICM hoists them past the VGPR
// budget and spills to scratch -> 3.5 GB of HBM scratch traffic (round 4).
//
// Algebra (round 6): hyperedge mean of affine map == affine map of hyperedge
// mean, so W/b are applied at the 100K-hyperedge level, never at 500K nodes.
// Empty hyperedge must produce 0 (not b) to match the reference.

// ---------------- he gather + transform: m[e] = (mean_{v in e} x[v]) @ W + b ----------------
__global__ void k_he_pull_xform(const float* __restrict__ x, const int* __restrict__ colptr,
                                const int* __restrict__ adjC, const float* __restrict__ W,
                                const float* __restrict__ bias, float* __restrict__ m) {
    __shared__ float Wl[CH * CH];
    for (int t = threadIdx.x; t < CH * CH; t += blockDim.x) Wl[t] = W[t];
    __syncthreads();
    const float4* Wl4 = (const float4*)Wl;
    const float4* x4 = (const float4*)x;
    float4* m4 = (float4*)m;
    int li  = threadIdx.x & 15;
    int gid = blockIdx.x * (blockDim.x >> 4) + (threadIdx.x >> 4);
    int ng  = gridDim.x * (blockDim.x >> 4);
    float4 bc = ((const float4*)bias)[li];
    for (int e = gid; e < N_HE; e += ng) {
        int s = colptr[e], en = colptr[e + 1];
        float4 acc = {0.f, 0.f, 0.f, 0.f};
        int p = s;
        for (; p + 8 <= en; p += 8) {
            int c0 = adjC[p], c1 = adjC[p+1], c2 = adjC[p+2], c3 = adjC[p+3];
            int c4 = adjC[p+4], c5 = adjC[p+5], c6 = adjC[p+6], c7 = adjC[p+7];
            float4 v0 = x4[(size_t)c0 * 16 + li];
            float4 v1 = x4[(size_t)c1 * 16 + li];
            float4 v2 = x4[(size_t)c2 * 16 + li];
            float4 v3 = x4[(size_t)c3 * 16 + li];
            float4 v4 = x4[(size_t)c4 * 16 + li];
            float4 v5 = x4[(size_t)c5 * 16 + li];
            float4 v6 = x4[(size_t)c6 * 16 + li];
            float4 v7 = x4[(size_t)c7 * 16 + li];
            acc.x += (v0.x + v1.x) + (v2.x + v3.x) + ((v4.x + v5.x) + (v6.x + v7.x));
            acc.y += (v0.y + v1.y) + (v2.y + v3.y) + ((v4.y + v5.y) + (v6.y + v7.y));
            acc.z += (v0.z + v1.z) + (v2.z + v3.z) + ((v4.z + v5.z) + (v6.z + v7.z));
            acc.w += (v0.w + v1.w) + (v2.w + v3.w) + ((v4.w + v5.w) + (v6.w + v7.w));
        }
        for (; p < en; ++p) {
            float4 v = x4[(size_t)adjC[p] * 16 + li];
            acc.x += v.x; acc.y += v.y; acc.z += v.z; acc.w += v.w;
        }
        if (en > s) {
            float binv = 1.0f / (float)(en - s);
            float4 h;
            h.x = acc.x * binv; h.y = acc.y * binv; h.z = acc.z * binv; h.w = acc.w * binv;
            float4 o = bc;
#pragma unroll 2
            for (int k0 = 0; k0 < 16; ++k0) {
                float a0 = __shfl(h.x, k0, 16);
                float a1 = __shfl(h.y, k0, 16);
                float a2 = __shfl(h.z, k0, 16);
                float a3 = __shfl(h.w, k0, 16);
                float4 w0 = Wl4[(k0 * 4 + 0) * 16 + li];
                float4 w1 = Wl4[(k0 * 4 + 1) * 16 + li];
                float4 w2 = Wl4[(k0 * 4 + 2) * 16 + li];
                float4 w3 = Wl4[(k0 * 4 + 3) * 16 + li];
                o.x = fmaf(a0, w0.x, o.x); o.y = fmaf(a0, w0.y, o.y);
                o.z = fmaf(a0, w0.z, o.z); o.w = fmaf(a0, w0.w, o.w);
                o.x = fmaf(a1, w1.x, o.x); o.y = fmaf(a1, w1.y, o.y);
                o.z = fmaf(a1, w1.z, o.z); o.w = fmaf(a1, w1.w, o.w);
                o.x = fmaf(a2, w2.x, o.x); o.y = fmaf(a2, w2.y, o.y);
                o.z = fmaf(a2, w2.z, o.z); o.w = fmaf(a2, w2.w, o.w);
                o.x = fmaf(a3, w3.x, o.x); o.y = fmaf(a3, w3.y, o.y);
                o.z = fmaf(a3, w3.z, o.z); o.w = fmaf(a3, w3.w, o.w);
            }
            m4[(size_t)e * 16 + li] = o;
        } else {
            float4 z = {0.f, 0.f, 0.f, 0.f};
            m4[(size_t)e * 16 + li] = z;   // empty hyperedge -> 0, not b
        }
    }
}

// helper: pull sum of m rows for node v (unroll 4)
__device__ __forceinline__ float4 pull4(const float4* __restrict__ m4, const int* __restrict__ adj,
                                        int s, int en, int li) {
    float4 acc = {0.f, 0.f, 0.f, 0.f};
    int p = s;
    for (; p + 4 <= en; p += 4) {
        int c0 = adj[p], c1 = adj[p+1], c2 = adj[p+2], c3 = adj[p+3];
        float4 v0 = m4[(size_t)c0 * 16 + li];
        float4 v1 = m4[(size_t)c1 * 16 + li];
        float4 v2 = m4[(size_t)c2 * 16 + li];
        float4 v3 = m4[(size_t)c3 * 16 + li];
        acc.x += (v0.x + v1.x) + (v2.x + v3.x);
        acc.y += (v0.y + v1.y) + (v2.y + v3.y);
        acc.z += (v0.z + v1.z) + (v2.z + v3.z);
        acc.w += (v0.w + v1.w) + (v2.w + v3.w);
    }
    for (; p < en; ++p) {
        float4 v = m4[(size_t)adj[p] * 16 + li];
        acc.x += v.x; acc.y += v.y; acc.z += v.z; acc.w += v.w;
    }
    return acc;
}

// ---------------- node pull + relu(.*Dinv): h[v] = relu(mean_{e: v in e} m[e]) ----------------
__global__ void k_node_pull_relu(const float* __restrict__ m, const int* __restrict__ rowptr,
                                 const int* __restrict__ adjR, float* __restrict__ h) {
    const float4* m4 = (const float4*)m;
    float4* h4 = (float4*)h;
    int li  = threadIdx.x & 15;
    int gid = blockIdx.x * (blockDim.x >> 4) + (threadIdx.x >> 4);
    int ng  = gridDim.x * (blockDim.x >> 4);
    for (int v = gid; v < N_NODES; v += ng) {
        int s = rowptr[v], en = rowptr[v + 1];
        float4 acc = pull4(m4, adjR, s, en, li);
        float dinv = (en > s) ? 1.0f / (float)(en - s) : 0.0f;
        float4 o;
        o.x = fmaxf(acc.x * dinv, 0.0f); o.y = fmaxf(acc.y * dinv, 0.0f);
        o.z = fmaxf(acc.z * dinv, 0.0f); o.w = fmaxf(acc.w * dinv, 0.0f);
        h4[(size_t)v * 16 + li] = o;
    }
}

// ---------------- node pull + relu(.*Dinv) + mean-pool accumulate ----------------
__global__ void k_node_pull_pool(const float* __restrict__ m, const int* __restrict__ rowptr,
                                 const int* __restrict__ adjR, const int* __restrict__ batch,
                                 float* __restrict__ pooled) {
    const float4* m4 = (const float4*)m;
    int li  = threadIdx.x & 15;
    int gid = blockIdx.x * (blockDim.x >> 4) + (threadIdx.x >> 4);
    int ng  = gridDim.x * (blockDim.x >> 4);
    int per = (N_NODES + ng - 1) / ng;
    int start = gid * per;
    int end = start + per; if (end > N_NODES) end = N_NODES;
    if (start >= end) return;
    float4 acc = {0.f, 0.f, 0.f, 0.f};
    int cur = batch[start];
    for (int v = start; v < end; ++v) {
        int s = rowptr[v], en = rowptr[v + 1];
        float4 h = pull4(m4, adjR, s, en, li);
        float dinv = (en > s) ? 1.0f / (float)(en - s) : 0.0f;
        int b = batch[v];
        if (b != cur) {
            float* dst = &pooled[(size_t)cur * CH + li * 4];
            atomicAdd(dst + 0, acc.x); atomicAdd(dst + 1, acc.y);
            atomicAdd(dst + 2, acc.z); atomicAdd(dst + 3, acc.w);
            acc.x = acc.y = acc.z = acc.w = 0.f;
            cur = b;
        }
        acc.x += fmaxf(h.x * dinv, 0.0f); acc.y += fmaxf(h.y * dinv, 0.0f);
        acc.z += fmaxf(h.z * dinv, 0.0f); acc.w += fmaxf(h.w * dinv, 0.0f);
    }
    float* dst = &pooled[(size_t)cur * CH + li * 4];
    atomicAdd(dst + 0, acc.x); atomicAdd(dst + 1, acc.y);
    atomicAdd(dst + 2, acc.z); atomicAdd(dst + 3, acc.w);
}

// ---------------- final: out[g] = (pooled[g]/max(cnt,1)) . Wfc + bfc ----------------
__global__ void k_final(const float* __restrict__ pooled, const int* __restrict__ gstart,
                        const float* __restrict__ Wfc, const float* __restrict__ bfc,
                        float* __restrict__ out) {
    int g = blockIdx.x;
    int lane = threadIdx.x;  // 64 threads
    float cnt = (float)(gstart[g + 1] - gstart[g]);
    cnt = fmaxf(cnt, 1.0f);
    float s = pooled[(size_t)g * CH + lane] / cnt;
    float p = s * Wfc[lane];
#pragma unroll
    for (int off = 32; off; off >>= 1) p += __shfl_down(p, off);
    if (lane == 0) out[g] = p + bfc[0];
}

extern "C" void kernel_launch(void* const* d_in, const int* in_sizes, int n_in,
                              void* d_out, int out_size, void* d_ws, size_t ws_size,
                              hipStream_t stream) {
    const float* x     = (const float*)d_in[0];
    const int*   ei    = (const int*)d_in[1];
    const int*   batch = (const int*)d_in[2];
    const float* W1    = (const float*)d_in[3];
    const float* b1    = (const float*)d_in[4];
    const float* W2    = (const float*)d_in[5];
    const float* b2    = (const float*)d_in[6];
    const float* Wfc   = (const float*)d_in[7];
    const float* bfc   = (const float*)d_in[8];
    float* out = (float*)d_out;

    const int* row = ei;
    const int* col = ei + NNZ;

    // ---- workspace carve-up (all offsets 256B-aligned) ----
    char* ws = (char*)d_ws;
    size_t off = 0;
    auto carve = [&](size_t bytes) {
        void* p = ws + off;
        off += (bytes + 255) & ~(size_t)255;
        return p;
    };
    float* bufH   = (float*)carve((size_t)N_NODES * CH * sizeof(float));  // 128 MB
    float* bufM   = (float*)carve((size_t)N_HE * CH * sizeof(float));     // 25.6 MB
    int*   adjR   = (int*)carve((size_t)NNZ * sizeof(int));               // 8 MB
    int*   adjC   = (int*)carve((size_t)NNZ * sizeof(int));               // 8 MB
    int*   Dcnt   = (int*)carve((size_t)N_NODES * sizeof(int));
    int*   Bcnt   = (int*)carve((size_t)N_HE * sizeof(int));
    int*   rowptr = (int*)carve((size_t)(N_NODES + 1) * sizeof(int));
    int*   colptr = (int*)carve((size_t)(N_HE + 1) * sizeof(int));
    int*   curR   = (int*)carve((size_t)N_NODES * sizeof(int));
    int*   curC   = (int*)carve((size_t)N_HE * sizeof(int));
    int*   bsR    = (int*)carve(512 * sizeof(int));
    int*   bsC    = (int*)carve(512 * sizeof(int));
    int*   gstart = (int*)carve((size_t)(N_G + 1) * sizeof(int));
    float* pooled = (float*)carve((size_t)N_G * CH * sizeof(float));

    const int nbR = (N_NODES + SCAN_CHUNK - 1) / SCAN_CHUNK;  // 489
    const int nbC = (N_HE + SCAN_CHUNK - 1) / SCAN_CHUNK;     // 98

    hipMemsetAsync(Dcnt, 0, (size_t)N_NODES * sizeof(int), stream);
    hipMemsetAsync(Bcnt, 0, (size_t)N_HE * sizeof(int), stream);
    hipMemsetAsync(pooled, 0, (size_t)N_G * CH * sizeof(float), stream);

    // build CSR both directions
    k_count<<<2048, 256, 0, stream>>>(row, col, Dcnt, Bcnt);
    k_scan1<<<nbR, SCAN_BLOCK, 0, stream>>>(Dcnt, N_NODES, bsR);
    k_scan2<<<1, 512, 0, stream>>>(bsR, nbR);
    k_scan3<<<nbR, SCAN_BLOCK, 0, stream>>>(Dcnt, N_NODES, bsR, rowptr, curR);
    k_scan1<<<nbC, SCAN_BLOCK, 0, stream>>>(Bcnt, N_HE, bsC);
    k_scan2<<<1, 512, 0, stream>>>(bsC, nbC);
    k_scan3<<<nbC, SCAN_BLOCK, 0, stream>>>(Bcnt, N_HE, bsC, colptr, curC);
    k_place<<<2048, 256, 0, stream>>>(row, col, curR, curC, adjR, adjC);
    k_bounds<<<3, 256, 0, stream>>>(batch, gstart);

    // conv1: m = (mean_e x) @ W1 + b1   (transform at hyperedge level)
    k_he_pull_xform<<<2048, 256, 0, stream>>>(x, colptr, adjC, W1, b1, bufM);
    // h = relu(mean_v m)
    k_node_pull_relu<<<2048, 256, 0, stream>>>(bufM, rowptr, adjR, bufH);
    // conv2: m2 = (mean_e h) @ W2 + b2
    k_he_pull_xform<<<2048, 256, 0, stream>>>(bufH, colptr, adjC, W2, b2, bufM);
    // conv2 node-pull fused with relu + mean-pool accumulation
    k_node_pull_pool<<<2048, 256, 0, stream>>>(bufM, rowptr, adjR, batch, pooled);
    k_final<<<N_G, 64, 0, stream>>>(pooled, gstart, Wfc, bfc, out);
}

// Round 10
// 939.892 us; speedup vs baseline: 3.2825x; 1.1967x over previous
//
#include <hip/hip_runtime.h>
#include <hip/hip_bf16.h>

#define N_NODES 500000
#define NNZ     2000000
#define N_HE    100000
#define N_G     512
#define CH      64

#define SCAN_BLOCK 256
#define SCAN_CHUNK 1024   // 4 items/thread

#define NB 8                              // placement buckets (one per XCD)
#define CB ((N_HE + NB - 1) / NB)         // hyperedge IDs per bucket
#define RB ((N_NODES + NB - 1) / NB)      // node IDs per bucket

// ---------------- degree counting ----------------
__global__ void k_count(const int* __restrict__ row, const int* __restrict__ col,
                        int* __restrict__ Dcnt, int* __restrict__ Bcnt) {
    int i = blockIdx.x * blockDim.x + threadIdx.x;
    int stride = gridDim.x * blockDim.x;
    for (; i < NNZ; i += stride) {
        atomicAdd(&Dcnt[row[i]], 1);
        atomicAdd(&Bcnt[col[i]], 1);
    }
}

// ---------------- hierarchical exclusive scan ----------------
__global__ void k_scan1(const int* __restrict__ in, int n, int* __restrict__ bsums) {
    __shared__ int lds[SCAN_BLOCK];
    int base = blockIdx.x * SCAN_CHUNK;
    int t = threadIdx.x;
    int s = 0;
#pragma unroll
    for (int j = 0; j < 4; ++j) { int idx = base + t * 4 + j; if (idx < n) s += in[idx]; }
    lds[t] = s; __syncthreads();
    for (int off = SCAN_BLOCK / 2; off; off >>= 1) {
        if (t < off) lds[t] += lds[t + off];
        __syncthreads();
    }
    if (t == 0) bsums[blockIdx.x] = lds[0];
}

__global__ void k_scan2(int* __restrict__ bsums, int nb) {
    __shared__ int lds[512];
    int t = threadIdx.x;
    int v = (t < nb) ? bsums[t] : 0;
    lds[t] = v; __syncthreads();
    for (int off = 1; off < 512; off <<= 1) {
        int add = (t >= off) ? lds[t - off] : 0;
        __syncthreads();
        lds[t] += add;
        __syncthreads();
    }
    if (t < nb) bsums[t] = lds[t] - v;   // exclusive
}

__global__ void k_scan3(const int* __restrict__ in, int n, const int* __restrict__ bsums,
                        int* __restrict__ outp, int* __restrict__ cursor) {
    __shared__ int lds[SCAN_BLOCK];
    int base = blockIdx.x * SCAN_CHUNK;
    int t = threadIdx.x;
    int v[4]; int s = 0;
#pragma unroll
    for (int j = 0; j < 4; ++j) { int idx = base + t * 4 + j; v[j] = (idx < n) ? in[idx] : 0; s += v[j]; }
    lds[t] = s; __syncthreads();
    for (int off = 1; off < SCAN_BLOCK; off <<= 1) {
        int add = (t >= off) ? lds[t - off] : 0;
        __syncthreads();
        lds[t] += add;
        __syncthreads();
    }
    int pref = bsums[blockIdx.x] + lds[t] - s;
#pragma unroll
    for (int j = 0; j < 4; ++j) {
        int idx = base + t * 4 + j;
        if (idx < n) {
            outp[idx] = pref;
            cursor[idx] = pref;
            pref += v[j];
            if (idx == n - 1) outp[n] = pref;
        }
    }
}

// ---------------- CSR placement, XCD-bucketed ----------------
// blockIdx%8 selects a contiguous ID-range bucket for BOTH directions; under
// round-robin block->XCD dispatch each bucket's ~1MB destination region and
// cursor slice stay resident in ONE XCD's L2, so the ~16 scattered 4B stores
// per 64B line combine before write-back (round 7: un-bucketed scatter wrote
// 255MB HBM for 16MB of adjacency). Plain stores (NOT nontemporal): lines
// must dwell in L2.
__global__ void k_place(const int* __restrict__ row, const int* __restrict__ col,
                        int* __restrict__ curR, int* __restrict__ curC,
                        int* __restrict__ adjR, int* __restrict__ adjC) {
    int bucket = blockIdx.x & (NB - 1);
    int bpos = blockIdx.x >> 3;          // index among this bucket's blocks
    int nbk  = gridDim.x >> 3;           // blocks per bucket
    int i = bpos * blockDim.x + threadIdx.x;
    int stride = nbk * blockDim.x;
    int clo = bucket * CB, chi = clo + CB;
    int rlo = bucket * RB, rhi = rlo + RB;
    for (; i < NNZ; i += stride) {
        int r = row[i], c = col[i];
        if (c >= clo && c < chi) {
            int p = atomicAdd(&curC[c], 1);
            adjC[p] = r;                 // hyperedge -> its nodes
        }
        if (r >= rlo && r < rhi) {
            int p = atomicAdd(&curR[r], 1);
            adjR[p] = c;                 // node -> its hyperedges
        }
    }
}

// ---------------- graph segment bounds (batch is sorted) ----------------
__global__ void k_bounds(const int* __restrict__ batch, int* __restrict__ gstart) {
    int g = blockIdx.x * blockDim.x + threadIdx.x;
    if (g > N_G) return;
    if (g == N_G) { gstart[g] = N_NODES; return; }
    int lo = 0, hi = N_NODES;
    while (lo < hi) {
        int mid = (lo + hi) >> 1;
        if (batch[mid] < g) lo = mid + 1; else hi = mid;
    }
    gstart[g] = lo;
}

// ======== heavy kernels: 16 lanes (float4) per row, 4 rows per wave ========
// NOTE: W-matmul loops use "#pragma unroll 2" deliberately. Full unroll exposes
// all 64 loop-invariant W float4 LDS reads; LICM hoists them past the VGPR
// budget and spills to scratch -> 3.5 GB of HBM scratch traffic (round 4).
//
// Algebra (round 6): hyperedge mean of affine map == affine map of hyperedge
// mean, so W/b are applied at the 100K-hyperedge level, never at 500K nodes.
// Empty hyperedge must produce 0 (not b) to match the reference.

// ---------------- he gather + transform: m[e] = (mean_{v in e} x[v]) @ W + b ----------------
__global__ void k_he_pull_xform(const float* __restrict__ x, const int* __restrict__ colptr,
                                const int* __restrict__ adjC, const float* __restrict__ W,
                                const float* __restrict__ bias, float* __restrict__ m) {
    __shared__ float Wl[CH * CH];
    for (int t = threadIdx.x; t < CH * CH; t += blockDim.x) Wl[t] = W[t];
    __syncthreads();
    const float4* Wl4 = (const float4*)Wl;
    const float4* x4 = (const float4*)x;
    float4* m4 = (float4*)m;
    int li  = threadIdx.x & 15;
    int gid = blockIdx.x * (blockDim.x >> 4) + (threadIdx.x >> 4);
    int ng  = gridDim.x * (blockDim.x >> 4);
    float4 bc = ((const float4*)bias)[li];
    for (int e = gid; e < N_HE; e += ng) {
        int s = colptr[e], en = colptr[e + 1];
        float4 acc = {0.f, 0.f, 0.f, 0.f};
        int p = s;
        for (; p + 8 <= en; p += 8) {
            int c0 = adjC[p], c1 = adjC[p+1], c2 = adjC[p+2], c3 = adjC[p+3];
            int c4 = adjC[p+4], c5 = adjC[p+5], c6 = adjC[p+6], c7 = adjC[p+7];
            float4 v0 = x4[(size_t)c0 * 16 + li];
            float4 v1 = x4[(size_t)c1 * 16 + li];
            float4 v2 = x4[(size_t)c2 * 16 + li];
            float4 v3 = x4[(size_t)c3 * 16 + li];
            float4 v4 = x4[(size_t)c4 * 16 + li];
            float4 v5 = x4[(size_t)c5 * 16 + li];
            float4 v6 = x4[(size_t)c6 * 16 + li];
            float4 v7 = x4[(size_t)c7 * 16 + li];
            acc.x += (v0.x + v1.x) + (v2.x + v3.x) + ((v4.x + v5.x) + (v6.x + v7.x));
            acc.y += (v0.y + v1.y) + (v2.y + v3.y) + ((v4.y + v5.y) + (v6.y + v7.y));
            acc.z += (v0.z + v1.z) + (v2.z + v3.z) + ((v4.z + v5.z) + (v6.z + v7.z));
            acc.w += (v0.w + v1.w) + (v2.w + v3.w) + ((v4.w + v5.w) + (v6.w + v7.w));
        }
        for (; p < en; ++p) {
            float4 v = x4[(size_t)adjC[p] * 16 + li];
            acc.x += v.x; acc.y += v.y; acc.z += v.z; acc.w += v.w;
        }
        if (en > s) {
            float binv = 1.0f / (float)(en - s);
            float4 h;
            h.x = acc.x * binv; h.y = acc.y * binv; h.z = acc.z * binv; h.w = acc.w * binv;
            float4 o = bc;
#pragma unroll 2
            for (int k0 = 0; k0 < 16; ++k0) {
                float a0 = __shfl(h.x, k0, 16);
                float a1 = __shfl(h.y, k0, 16);
                float a2 = __shfl(h.z, k0, 16);
                float a3 = __shfl(h.w, k0, 16);
                float4 w0 = Wl4[(k0 * 4 + 0) * 16 + li];
                float4 w1 = Wl4[(k0 * 4 + 1) * 16 + li];
                float4 w2 = Wl4[(k0 * 4 + 2) * 16 + li];
                float4 w3 = Wl4[(k0 * 4 + 3) * 16 + li];
                o.x = fmaf(a0, w0.x, o.x); o.y = fmaf(a0, w0.y, o.y);
                o.z = fmaf(a0, w0.z, o.z); o.w = fmaf(a0, w0.w, o.w);
                o.x = fmaf(a1, w1.x, o.x); o.y = fmaf(a1, w1.y, o.y);
                o.z = fmaf(a1, w1.z, o.z); o.w = fmaf(a1, w1.w, o.w);
                o.x = fmaf(a2, w2.x, o.x); o.y = fmaf(a2, w2.y, o.y);
                o.z = fmaf(a2, w2.z, o.z); o.w = fmaf(a2, w2.w, o.w);
                o.x = fmaf(a3, w3.x, o.x); o.y = fmaf(a3, w3.y, o.y);
                o.z = fmaf(a3, w3.z, o.z); o.w = fmaf(a3, w3.w, o.w);
            }
            m4[(size_t)e * 16 + li] = o;
        } else {
            float4 z = {0.f, 0.f, 0.f, 0.f};
            m4[(size_t)e * 16 + li] = z;   // empty hyperedge -> 0, not b
        }
    }
}

// helper: pull sum of m rows for node v (unroll 4)
__device__ __forceinline__ float4 pull4(const float4* __restrict__ m4, const int* __restrict__ adj,
                                        int s, int en, int li) {
    float4 acc = {0.f, 0.f, 0.f, 0.f};
    int p = s;
    for (; p + 4 <= en; p += 4) {
        int c0 = adj[p], c1 = adj[p+1], c2 = adj[p+2], c3 = adj[p+3];
        float4 v0 = m4[(size_t)c0 * 16 + li];
        float4 v1 = m4[(size_t)c1 * 16 + li];
        float4 v2 = m4[(size_t)c2 * 16 + li];
        float4 v3 = m4[(size_t)c3 * 16 + li];
        acc.x += (v0.x + v1.x) + (v2.x + v3.x);
        acc.y += (v0.y + v1.y) + (v2.y + v3.y);
        acc.z += (v0.z + v1.z) + (v2.z + v3.z);
        acc.w += (v0.w + v1.w) + (v2.w + v3.w);
    }
    for (; p < en; ++p) {
        float4 v = m4[(size_t)adj[p] * 16 + li];
        acc.x += v.x; acc.y += v.y; acc.z += v.z; acc.w += v.w;
    }
    return acc;
}

// ---------------- node pull + relu(.*Dinv): h[v] = relu(mean_{e: v in e} m[e]) ----------------
__global__ void k_node_pull_relu(const float* __restrict__ m, const int* __restrict__ rowptr,
                                 const int* __restrict__ adjR, float* __restrict__ h) {
    const float4* m4 = (const float4*)m;
    float4* h4 = (float4*)h;
    int li  = threadIdx.x & 15;
    int gid = blockIdx.x * (blockDim.x >> 4) + (threadIdx.x >> 4);
    int ng  = gridDim.x * (blockDim.x >> 4);
    for (int v = gid; v < N_NODES; v += ng) {
        int s = rowptr[v], en = rowptr[v + 1];
        float4 acc = pull4(m4, adjR, s, en, li);
        float dinv = (en > s) ? 1.0f / (float)(en - s) : 0.0f;
        float4 o;
        o.x = fmaxf(acc.x * dinv, 0.0f); o.y = fmaxf(acc.y * dinv, 0.0f);
        o.z = fmaxf(acc.z * dinv, 0.0f); o.w = fmaxf(acc.w * dinv, 0.0f);
        h4[(size_t)v * 16 + li] = o;
    }
}

// ---------------- node pull + relu(.*Dinv) + mean-pool accumulate ----------------
__global__ void k_node_pull_pool(const float* __restrict__ m, const int* __restrict__ rowptr,
                                 const int* __restrict__ adjR, const int* __restrict__ batch,
                                 float* __restrict__ pooled) {
    const float4* m4 = (const float4*)m;
    int li  = threadIdx.x & 15;
    int gid = blockIdx.x * (blockDim.x >> 4) + (threadIdx.x >> 4);
    int ng  = gridDim.x * (blockDim.x >> 4);
    int per = (N_NODES + ng - 1) / ng;
    int start = gid * per;
    int end = start + per; if (end > N_NODES) end = N_NODES;
    if (start >= end) return;
    float4 acc = {0.f, 0.f, 0.f, 0.f};
    int cur = batch[start];
    for (int v = start; v < end; ++v) {
        int s = rowptr[v], en = rowptr[v + 1];
        float4 h = pull4(m4, adjR, s, en, li);
        float dinv = (en > s) ? 1.0f / (float)(en - s) : 0.0f;
        int b = batch[v];
        if (b != cur) {
            float* dst = &pooled[(size_t)cur * CH + li * 4];
            atomicAdd(dst + 0, acc.x); atomicAdd(dst + 1, acc.y);
            atomicAdd(dst + 2, acc.z); atomicAdd(dst + 3, acc.w);
            acc.x = acc.y = acc.z = acc.w = 0.f;
            cur = b;
        }
        acc.x += fmaxf(h.x * dinv, 0.0f); acc.y += fmaxf(h.y * dinv, 0.0f);
        acc.z += fmaxf(h.z * dinv, 0.0f); acc.w += fmaxf(h.w * dinv, 0.0f);
    }
    float* dst = &pooled[(size_t)cur * CH + li * 4];
    atomicAdd(dst + 0, acc.x); atomicAdd(dst + 1, acc.y);
    atomicAdd(dst + 2, acc.z); atomicAdd(dst + 3, acc.w);
}

// ---------------- final: out[g] = (pooled[g]/max(cnt,1)) . Wfc + bfc ----------------
__global__ void k_final(const float* __restrict__ pooled, const int* __restrict__ gstart,
                        const float* __restrict__ Wfc, const float* __restrict__ bfc,
                        float* __restrict__ out) {
    int g = blockIdx.x;
    int lane = threadIdx.x;  // 64 threads
    float cnt = (float)(gstart[g + 1] - gstart[g]);
    cnt = fmaxf(cnt, 1.0f);
    float s = pooled[(size_t)g * CH + lane] / cnt;
    float p = s * Wfc[lane];
#pragma unroll
    for (int off = 32; off; off >>= 1) p += __shfl_down(p, off);
    if (lane == 0) out[g] = p + bfc[0];
}

extern "C" void kernel_launch(void* const* d_in, const int* in_sizes, int n_in,
                              void* d_out, int out_size, void* d_ws, size_t ws_size,
                              hipStream_t stream) {
    const float* x     = (const float*)d_in[0];
    const int*   ei    = (const int*)d_in[1];
    const int*   batch = (const int*)d_in[2];
    const float* W1    = (const float*)d_in[3];
    const float* b1    = (const float*)d_in[4];
    const float* W2    = (const float*)d_in[5];
    const float* b2    = (const float*)d_in[6];
    const float* Wfc   = (const float*)d_in[7];
    const float* bfc   = (const float*)d_in[8];
    float* out = (float*)d_out;

    const int* row = ei;
    const int* col = ei + NNZ;

    // ---- workspace carve-up (all offsets 256B-aligned) ----
    char* ws = (char*)d_ws;
    size_t off = 0;
    auto carve = [&](size_t bytes) {
        void* p = ws + off;
        off += (bytes + 255) & ~(size_t)255;
        return p;
    };
    float* bufH   = (float*)carve((size_t)N_NODES * CH * sizeof(float));  // 128 MB
    float* bufM   = (float*)carve((size_t)N_HE * CH * sizeof(float));     // 25.6 MB
    int*   adjR   = (int*)carve((size_t)NNZ * sizeof(int));               // 8 MB
    int*   adjC   = (int*)carve((size_t)NNZ * sizeof(int));               // 8 MB
    int*   Dcnt   = (int*)carve((size_t)N_NODES * sizeof(int));
    int*   Bcnt   = (int*)carve((size_t)N_HE * sizeof(int));
    int*   rowptr = (int*)carve((size_t)(N_NODES + 1) * sizeof(int));
    int*   colptr = (int*)carve((size_t)(N_HE + 1) * sizeof(int));
    int*   curR   = (int*)carve((size_t)N_NODES * sizeof(int));
    int*   curC   = (int*)carve((size_t)N_HE * sizeof(int));
    int*   bsR    = (int*)carve(512 * sizeof(int));
    int*   bsC    = (int*)carve(512 * sizeof(int));
    int*   gstart = (int*)carve((size_t)(N_G + 1) * sizeof(int));
    float* pooled = (float*)carve((size_t)N_G * CH * sizeof(float));

    const int nbR = (N_NODES + SCAN_CHUNK - 1) / SCAN_CHUNK;  // 489
    const int nbC = (N_HE + SCAN_CHUNK - 1) / SCAN_CHUNK;     // 98

    hipMemsetAsync(Dcnt, 0, (size_t)N_NODES * sizeof(int), stream);
    hipMemsetAsync(Bcnt, 0, (size_t)N_HE * sizeof(int), stream);
    hipMemsetAsync(pooled, 0, (size_t)N_G * CH * sizeof(float), stream);

    // build CSR both directions
    k_count<<<2048, 256, 0, stream>>>(row, col, Dcnt, Bcnt);
    k_scan1<<<nbR, SCAN_BLOCK, 0, stream>>>(Dcnt, N_NODES, bsR);
    k_scan2<<<1, 512, 0, stream>>>(bsR, nbR);
    k_scan3<<<nbR, SCAN_BLOCK, 0, stream>>>(Dcnt, N_NODES, bsR, rowptr, curR);
    k_scan1<<<nbC, SCAN_BLOCK, 0, stream>>>(Bcnt, N_HE, bsC);
    k_scan2<<<1, 512, 0, stream>>>(bsC, nbC);
    k_scan3<<<nbC, SCAN_BLOCK, 0, stream>>>(Bcnt, N_HE, bsC, colptr, curC);
    k_place<<<2048, 256, 0, stream>>>(row, col, curR, curC, adjR, adjC);
    k_bounds<<<3, 256, 0, stream>>>(batch, gstart);

    // conv1: m = (mean_e x) @ W1 + b1   (transform at hyperedge level)
    k_he_pull_xform<<<2048, 256, 0, stream>>>(x, colptr, adjC, W1, b1, bufM);
    // h = relu(mean_v m)
    k_node_pull_relu<<<2048, 256, 0, stream>>>(bufM, rowptr, adjR, bufH);
    // conv2: m2 = (mean_e h) @ W2 + b2
    k_he_pull_xform<<<2048, 256, 0, stream>>>(bufH, colptr, adjC, W2, b2, bufM);
    // conv2 node-pull fused with relu + mean-pool accumulation
    k_node_pull_pool<<<2048, 256, 0, stream>>>(bufM, rowptr, adjR, batch, pooled);
    k_final<<<N_G, 64, 0, stream>>>(pooled, gstart, Wfc, bfc, out);
}